// Round 5
// baseline (161.233 us; speedup 1.0000x reference)
//
#include <hip/hip_runtime.h>
#include <hip/hip_bf16.h>

typedef __attribute__((ext_vector_type(8))) short bf16x8;
typedef __attribute__((ext_vector_type(4))) float f32x4;

#define S_LEN 2048
#define EMB   1024
#define NH    16
#define HD    64

// XOR-swizzled LDS addressing: 64-col bf16 tiles, 8-elem (16 B) chunks.
// elem(row, chunk) = row*64 + ((chunk ^ (row&7))*8).
// Verified: SQ_LDS_BANK_CONFLICT == 0.
__device__ inline int swz(int row, int chunk) {
  return row * 64 + ((chunk ^ (row & 7)) << 3);
}

// 128-col variant (16 chunks/row) for the V tile [dim][key] at KVBLK=128.
__device__ inline int swz128(int row, int chunk) {
  return row * 128 + ((chunk ^ (row & 15)) << 3);
}

// K-row permutation: storing K row s at position [s5,s2,s4,s3,s1,s0] makes
// the exp(S^T) C-layout registers exactly the mfma_16x16x32 A-fragment for
// natural-order V; PV uses K=32 MFMA with b128 V reads, no fixup.
// At KVBLK=128 it applies within each 64-key half (bit 6 preserved).
__device__ inline int kperm(int s) {
  return (s & 0x23) | ((s & 0x04) << 2) | ((s & 0x18) >> 1);
}

// Convert 8 contiguous f32 -> 8 bf16 (RNE) packed in a uint4, optional scale.
__device__ inline uint4 cvt8(const float* __restrict__ src, float scale) {
  float4 f0 = ((const float4*)src)[0];
  float4 f1 = ((const float4*)src)[1];
  __hip_bfloat16 t[8];
  t[0] = __float2bfloat16(f0.x * scale);
  t[1] = __float2bfloat16(f0.y * scale);
  t[2] = __float2bfloat16(f0.z * scale);
  t[3] = __float2bfloat16(f0.w * scale);
  t[4] = __float2bfloat16(f1.x * scale);
  t[5] = __float2bfloat16(f1.y * scale);
  t[6] = __float2bfloat16(f1.z * scale);
  t[7] = __float2bfloat16(f1.w * scale);
  return *(uint4*)t;
}

// ---------------------------------------------------------------------------
// prep: z<2 -> K/V reformat for batch b=z; z==2 -> W f32->bf16 convert.
//   Kb[((b*NH+h)*S + s)*64 + d]  (head-major, rows = keys)
//   Vt[((b*NH+h)*64 + d)*S + s]  (transposed, rows = dims)
// (unchanged)
// ---------------------------------------------------------------------------
__global__ __launch_bounds__(256)
void prep(const float* __restrict__ K, const float* __restrict__ V,
          const float* __restrict__ W,
          __hip_bfloat16* __restrict__ Kb, __hip_bfloat16* __restrict__ Vt,
          __hip_bfloat16* __restrict__ Wb) {
  const int tid = threadIdx.x;
  if (blockIdx.z == 2) {   // W convert: 512 virtual blocks x 2048 elems
    const int widx = blockIdx.y * 32 + blockIdx.x;
    const int i = (widx * 256 + tid) * 8;
    *(uint4*)(Wb + i) = cvt8(W + i, 1.0f);
    return;
  }
  __shared__ float vt[64 * 65];
  const int st = blockIdx.x, h = blockIdx.y, b = blockIdx.z;
  const size_t srcbase = ((size_t)(b * S_LEN + st * 64)) * EMB + h * HD;
  const size_t kvb = ((size_t)(b * NH + h) * S_LEN + st * 64) * HD;
  const size_t vtb = ((size_t)(b * NH + h) * HD) * S_LEN + st * 64;

  for (int c = tid; c < 512; c += 256) {
    const int r = c >> 3, c8 = (c & 7) * 8;
    *(uint4*)(Kb + kvb + r * HD + c8) = cvt8(K + srcbase + (size_t)r * EMB + c8, 1.0f);
    const float* vsrc = V + srcbase + (size_t)r * EMB + c8;
    float4 a = ((const float4*)vsrc)[0];
    float4 d4 = ((const float4*)vsrc)[1];
    float tv[8] = {a.x, a.y, a.z, a.w, d4.x, d4.y, d4.z, d4.w};
    #pragma unroll
    for (int j = 0; j < 8; ++j) vt[r * 65 + c8 + j] = tv[j];
  }
  __syncthreads();
  for (int c = tid; c < 512; c += 256) {
    const int d = c >> 3, s8 = (c & 7) * 8;
    __hip_bfloat16 t[8];
    #pragma unroll
    for (int j = 0; j < 8; ++j)
      t[j] = __float2bfloat16(vt[(s8 + j) * 65 + d]);
    *(uint4*)(Vt + vtb + (size_t)d * S_LEN + s8) = *(uint4*)t;
  }
}

// ---------------------------------------------------------------------------
// Flash attention, R13 (frozen — verified 46.5 us, MfmaUtil 33, absmax
// 4.88e-4). 16 QK MFMAs back-to-back; exp/pack half-A; PV t=0,1 overlapping
// exp/pack half-B; PV t=2,3. setprio around MFMA clusters. exp2 via raw
// v_exp_f32; elementwise bf16 cvt (compiler pairs to v_cvt_pk). lsum on the
// MFMA pipe. KVBLK=128, double-buffered, 1 barrier/iter, 80 KB LDS.
// ---------------------------------------------------------------------------
__global__ __launch_bounds__(512, 4)
void attn_fwd(const float* __restrict__ Q,
              const __hip_bfloat16* __restrict__ Kb,
              const __hip_bfloat16* __restrict__ Vt,
              __hip_bfloat16* __restrict__ O)
{
  __shared__ __align__(16) __hip_bfloat16 qs[128 * 64];      // 16 KB
  __shared__ __align__(16) __hip_bfloat16 ks[2][128 * 64];   // 32 KB [key][dim]
  __shared__ __align__(16) __hip_bfloat16 vs[2][64 * 128];   // 32 KB [dim][key]

  const int qt   = blockIdx.x;
  const int h    = blockIdx.y;
  const int b    = blockIdx.z;
  const int tid  = threadIdx.x;
  const int wave = tid >> 6;
  const int lane = tid & 63;
  const int ln   = lane & 15;
  const int qd   = lane >> 4;

  const size_t baseQ = ((size_t)(b * S_LEN + qt * 128)) * EMB + h * HD;
  const size_t kvb   = ((size_t)(b * NH + h) * S_LEN) * HD;
  const size_t vtb   = ((size_t)(b * NH + h) * HD) * S_LEN;

  // staging maps (loop-invariant write addrs)
  const int r0 = tid >> 3, cc = tid & 7;
  const int kpos0 = swz(kperm(r0), cc);
  const int kpos1 = kpos0 + 64 * 64;           // kperm within half, bit6 kept
  const int vr0 = tid >> 4, vch = tid & 15;
  const int vpos0 = swz128(vr0, vch);
  const int vpos1 = vpos0 + 32 * 128;          // (vr0+32)&15 == vr0&15

  // prefetch tile 0
  uint4 kreg0 = *(const uint4*)(Kb + kvb + (size_t)(r0)       * HD + cc * 8);
  uint4 kreg1 = *(const uint4*)(Kb + kvb + (size_t)(64 + r0)  * HD + cc * 8);
  uint4 vreg0 = *(const uint4*)(Vt + vtb + (size_t)vr0        * S_LEN + vch * 8);
  uint4 vreg1 = *(const uint4*)(Vt + vtb + (size_t)(vr0 + 32) * S_LEN + vch * 8);

  // stage Q (f32 -> bf16, scale = 0.125*log2(e); P = exp2(S'))
  const float qscale = 0.125f * 1.44269504088896f;
  #pragma unroll
  for (int i = 0; i < 2; ++i) {
    const int c = tid + 512 * i, row = c >> 3, ch = c & 7;
    *(uint4*)&qs[swz(row, ch)] = cvt8(Q + baseQ + (size_t)row * EMB + ch * 8, qscale);
  }
  // write tile 0, prefetch tile 1
  *(uint4*)&ks[0][kpos0] = kreg0;
  *(uint4*)&ks[0][kpos1] = kreg1;
  *(uint4*)&vs[0][vpos0] = vreg0;
  *(uint4*)&vs[0][vpos1] = vreg1;
  kreg0 = *(const uint4*)(Kb + kvb + (size_t)(128 + r0)      * HD + cc * 8);
  kreg1 = *(const uint4*)(Kb + kvb + (size_t)(192 + r0)      * HD + cc * 8);
  vreg0 = *(const uint4*)(Vt + vtb + (size_t)vr0        * S_LEN + 128 + vch * 8);
  vreg1 = *(const uint4*)(Vt + vtb + (size_t)(vr0 + 32) * S_LEN + 128 + vch * 8);
  __syncthreads();   // qs + buf0 ready

  // Q B-fragments (n = query = ln, k = qd*8+j), loop-invariant
  bf16x8 aq[2];
  #pragma unroll
  for (int kh = 0; kh < 2; ++kh)
    aq[kh] = *(const bf16x8*)&qs[swz(wave * 16 + ln, kh * 4 + qd)];

  // ones B-fragment for lsum-on-MFMA: D[q][*] = sum_k P[q][k]
  bf16x8 ones;
  #pragma unroll
  for (int j = 0; j < 8; ++j) ones[j] = (short)0x3F80;   // bf16 1.0

  f32x4 oacc[4] = {};   // [dn]; C: col=dim=ln, row=query=qd*4+r
  f32x4 lacc = {};      // row sums; C: row=query=qd*4+r (col replicated)

  for (int kt = 0; kt < S_LEN / 128; ++kt) {
    const int cur = kt & 1;
    if (kt + 1 < S_LEN / 128) {     // regs loaded one full iter ago: no stall
      *(uint4*)&ks[1 - cur][kpos0] = kreg0;
      *(uint4*)&ks[1 - cur][kpos1] = kreg1;
      *(uint4*)&vs[1 - cur][vpos0] = vreg0;
      *(uint4*)&vs[1 - cur][vpos1] = vreg1;
      if (kt + 2 < S_LEN / 128) {
        const int kb2 = (kt + 2) * 128;
        kreg0 = *(const uint4*)(Kb + kvb + (size_t)(kb2 + r0)       * HD + cc * 8);
        kreg1 = *(const uint4*)(Kb + kvb + (size_t)(kb2 + 64 + r0)  * HD + cc * 8);
        vreg0 = *(const uint4*)(Vt + vtb + (size_t)vr0        * S_LEN + kb2 + vch * 8);
        vreg1 = *(const uint4*)(Vt + vtb + (size_t)(vr0 + 32) * S_LEN + kb2 + vch * 8);
      }
    }

    // ---- S^T = K Q^T, both 64-key halves back-to-back: 16 independent
    // MFMAs fill the matrix pipe while the trans pipe is still free.
    f32x4 sfA[4], sfB[4];
    __builtin_amdgcn_s_setprio(1);
    #pragma unroll
    for (int k16 = 0; k16 < 4; ++k16) {
      const int krow = k16 * 16 + ln;
      bf16x8 ak0 = *(const bf16x8*)&ks[cur][swz(krow, qd)];
      bf16x8 ak1 = *(const bf16x8*)&ks[cur][swz(krow, 4 + qd)];
      f32x4 acc = {};
      acc = __builtin_amdgcn_mfma_f32_16x16x32_bf16(ak0, aq[0], acc, 0, 0, 0);
      sfA[k16] = __builtin_amdgcn_mfma_f32_16x16x32_bf16(ak1, aq[1], acc, 0, 0, 0);
    }
    #pragma unroll
    for (int k16 = 0; k16 < 4; ++k16) {
      const int krow = (4 + k16) * 16 + ln;
      bf16x8 ak0 = *(const bf16x8*)&ks[cur][swz(krow, qd)];
      bf16x8 ak1 = *(const bf16x8*)&ks[cur][swz(krow, 4 + qd)];
      f32x4 acc = {};
      acc = __builtin_amdgcn_mfma_f32_16x16x32_bf16(ak0, aq[0], acc, 0, 0, 0);
      sfB[k16] = __builtin_amdgcn_mfma_f32_16x16x32_bf16(ak1, aq[1], acc, 0, 0, 0);
    }
    __builtin_amdgcn_s_setprio(0);

    // ---- exp/pack half A -> apA[0..1] (trans pipe; overlaps QK-B tail) ----
    bf16x8 apA[2];
    #pragma unroll
    for (int t2 = 0; t2 < 2; ++t2)
      #pragma unroll
      for (int j = 0; j < 8; ++j) {
        const float p = __builtin_amdgcn_exp2f(sfA[t2 * 2 + (j >> 2)][j & 3]);
        __hip_bfloat16 hb = __float2bfloat16(p);
        apA[t2][j] = *(short*)&hb;
      }

    // ---- PV + lsum for t=0,1 (10 MFMA) — overlaps exp/pack of half B ----
    __builtin_amdgcn_s_setprio(1);
    #pragma unroll
    for (int t = 0; t < 2; ++t) {
      lacc = __builtin_amdgcn_mfma_f32_16x16x32_bf16(apA[t], ones, lacc, 0, 0, 0);
      #pragma unroll
      for (int dn = 0; dn < 4; ++dn) {
        bf16x8 bv = *(const bf16x8*)&vs[cur][swz128(dn * 16 + ln, t * 4 + qd)];
        oacc[dn] = __builtin_amdgcn_mfma_f32_16x16x32_bf16(apA[t], bv, oacc[dn], 0, 0, 0);
      }
    }
    __builtin_amdgcn_s_setprio(0);

    // ---- exp/pack half B -> apB[0..1] ----
    bf16x8 apB[2];
    #pragma unroll
    for (int t2 = 0; t2 < 2; ++t2)
      #pragma unroll
      for (int j = 0; j < 8; ++j) {
        const float p = __builtin_amdgcn_exp2f(sfB[t2 * 2 + (j >> 2)][j & 3]);
        __hip_bfloat16 hb = __float2bfloat16(p);
        apB[t2][j] = *(short*)&hb;
      }

    // ---- PV + lsum for t=2,3 ----
    __builtin_amdgcn_s_setprio(1);
    #pragma unroll
    for (int t = 0; t < 2; ++t) {
      lacc = __builtin_amdgcn_mfma_f32_16x16x32_bf16(apB[t], ones, lacc, 0, 0, 0);
      #pragma unroll
      for (int dn = 0; dn < 4; ++dn) {
        bf16x8 bv = *(const bf16x8*)&vs[cur][swz128(dn * 16 + ln, (2 + t) * 4 + qd)];
        oacc[dn] = __builtin_amdgcn_mfma_f32_16x16x32_bf16(apB[t], bv, oacc[dn], 0, 0, 0);
      }
    }
    __builtin_amdgcn_s_setprio(0);

    __syncthreads();   // single barrier per iteration
  }

  // ---- epilogue: lacc[r] is already this lane's row sums -> normalize ----
  #pragma unroll
  for (int r = 0; r < 4; ++r) {
    const float inv = 1.f / lacc[r];
    const int row = wave * 16 + qd * 4 + r;
    #pragma unroll
    for (int dn = 0; dn < 4; ++dn)
      O[baseQ + (size_t)row * EMB + dn * 16 + ln] =
          __float2bfloat16(oacc[dn][r] * inv);
  }
}

// ---------------------------------------------------------------------------
// Projection R14: split-K=2. R11's re-tile changed the tile but NOT
// waves/SIMD (2 both ways) — which is why the total never moved. At 4M output
// elems the only way to raise occupancy is split-K: grid (32,16,2) = 1024
// blocks, z = K-half, LDS 48 KB -> 3 blocks/CU = 12 waves/CU = 3 waves/SIMD.
// Writes f32 partials (no bias); proj_reduce sums + bias + PReLU.
// Body otherwise identical to the verified v5 (swizzle, dbuf, reg prefetch).
// ---------------------------------------------------------------------------
__global__ __launch_bounds__(256, 3)
void proj_gemm(const __hip_bfloat16* __restrict__ X,
               const __hip_bfloat16* __restrict__ Wb,
               float* __restrict__ P0,
               float* __restrict__ P1)
{
  __shared__ __align__(16) __hip_bfloat16 xs[2][128 * 64];   // 32 KB
  __shared__ __align__(16) __hip_bfloat16 wsm[2][64 * 64];   // 16 KB

  const int m0   = blockIdx.x * 128;
  const int n0   = blockIdx.y * 64;
  const int kb0  = blockIdx.z * 512;           // element offset of this K-half
  float* __restrict__ P = blockIdx.z ? P1 : P0;
  const int tid  = threadIdx.x;
  const int wave = tid >> 6;
  const int wm   = wave >> 1;      // 0..1 : 64-row half
  const int wn   = wave & 1;       // 0..1 : 32-col half
  const int lane = tid & 63;
  const int ln   = lane & 15;
  const int qd   = lane >> 4;

  // staging: X 1024 chunks / 256 thr = 4 each; W 512 chunks = 2 each
  const int r0 = tid >> 3, cc = tid & 7;

  f32x4 acc[8] = {};   // [mf*2+nf]

  uint4 xg0, xg1, xg2, xg3, wg0, wg1;
  #define LOADK(ko)                                                           \
    xg0 = *(const uint4*)(X  + (size_t)(m0 + r0     ) * EMB + (ko) + cc * 8); \
    xg1 = *(const uint4*)(X  + (size_t)(m0 + r0 + 32) * EMB + (ko) + cc * 8); \
    xg2 = *(const uint4*)(X  + (size_t)(m0 + r0 + 64) * EMB + (ko) + cc * 8); \
    xg3 = *(const uint4*)(X  + (size_t)(m0 + r0 + 96) * EMB + (ko) + cc * 8); \
    wg0 = *(const uint4*)(Wb + (size_t)(n0 + r0     ) * EMB + (ko) + cc * 8); \
    wg1 = *(const uint4*)(Wb + (size_t)(n0 + r0 + 32) * EMB + (ko) + cc * 8)
  #define STORELDS(buf)                                                       \
    *(uint4*)&xs [buf][swz(r0,      cc)] = xg0;                               \
    *(uint4*)&xs [buf][swz(r0 + 32, cc)] = xg1;                               \
    *(uint4*)&xs [buf][swz(r0 + 64, cc)] = xg2;                               \
    *(uint4*)&xs [buf][swz(r0 + 96, cc)] = xg3;                               \
    *(uint4*)&wsm[buf][swz(r0,      cc)] = wg0;                               \
    *(uint4*)&wsm[buf][swz(r0 + 32, cc)] = wg1

  LOADK(kb0);
  STORELDS(0);
  LOADK(kb0 + 64);
  __syncthreads();

  for (int kt = 0; kt < 8; ++kt) {             // 8 x BK=64 = this K-half
    const int cur = kt & 1;
    if (kt + 1 < 8) {
      STORELDS(1 - cur);
      if (kt + 2 < 8) {
        LOADK(kb0 + (kt + 2) * 64);
      }
    }

    #pragma unroll
    for (int ks2 = 0; ks2 < 2; ++ks2) {   // two K=32 steps
      bf16x8 ax0 = *(const bf16x8*)&xs[cur][swz(wm * 64 +  0 + ln, ks2 * 4 + qd)];
      bf16x8 ax1 = *(const bf16x8*)&xs[cur][swz(wm * 64 + 16 + ln, ks2 * 4 + qd)];
      bf16x8 ax2 = *(const bf16x8*)&xs[cur][swz(wm * 64 + 32 + ln, ks2 * 4 + qd)];
      bf16x8 ax3 = *(const bf16x8*)&xs[cur][swz(wm * 64 + 48 + ln, ks2 * 4 + qd)];
      bf16x8 bw0 = *(const bf16x8*)&wsm[cur][swz(wn * 32 +  0 + ln, ks2 * 4 + qd)];
      bf16x8 bw1 = *(const bf16x8*)&wsm[cur][swz(wn * 32 + 16 + ln, ks2 * 4 + qd)];
      acc[0] = __builtin_amdgcn_mfma_f32_16x16x32_bf16(ax0, bw0, acc[0], 0, 0, 0);
      acc[1] = __builtin_amdgcn_mfma_f32_16x16x32_bf16(ax0, bw1, acc[1], 0, 0, 0);
      acc[2] = __builtin_amdgcn_mfma_f32_16x16x32_bf16(ax1, bw0, acc[2], 0, 0, 0);
      acc[3] = __builtin_amdgcn_mfma_f32_16x16x32_bf16(ax1, bw1, acc[3], 0, 0, 0);
      acc[4] = __builtin_amdgcn_mfma_f32_16x16x32_bf16(ax2, bw0, acc[4], 0, 0, 0);
      acc[5] = __builtin_amdgcn_mfma_f32_16x16x32_bf16(ax2, bw1, acc[5], 0, 0, 0);
      acc[6] = __builtin_amdgcn_mfma_f32_16x16x32_bf16(ax3, bw0, acc[6], 0, 0, 0);
      acc[7] = __builtin_amdgcn_mfma_f32_16x16x32_bf16(ax3, bw1, acc[7], 0, 0, 0);
    }
    __syncthreads();
  }

  #pragma unroll
  for (int mf = 0; mf < 4; ++mf)
    #pragma unroll
    for (int nf = 0; nf < 2; ++nf)
      #pragma unroll
      for (int r = 0; r < 4; ++r)
        P[(size_t)(m0 + wm * 64 + mf * 16 + qd * 4 + r) * EMB +
          n0 + wn * 32 + nf * 16 + ln] = acc[mf * 2 + nf][r];
  #undef LOADK
  #undef STORELDS
}

// Out = PReLU(P0 + P1 + b). 2048 blocks x 256 thr x 8 elems. ~50 MB traffic.
__global__ __launch_bounds__(256)
void proj_reduce(const float* __restrict__ P0, const float* __restrict__ P1,
                 const float* __restrict__ Bv, const float* __restrict__ Pa,
                 float* __restrict__ Out)
{
  const float a = Pa[0];
  const size_t i = ((size_t)blockIdx.x * 256 + threadIdx.x) * 8;
  const int col = (int)(i & (EMB - 1));
  float4 x0 = ((const float4*)(P0 + i))[0], x1 = ((const float4*)(P0 + i))[1];
  float4 y0 = ((const float4*)(P1 + i))[0], y1 = ((const float4*)(P1 + i))[1];
  float4 b0 = ((const float4*)(Bv + col))[0], b1 = ((const float4*)(Bv + col))[1];
  float v[8] = {x0.x + y0.x + b0.x, x0.y + y0.y + b0.y,
                x0.z + y0.z + b0.z, x0.w + y0.w + b0.w,
                x1.x + y1.x + b1.x, x1.y + y1.y + b1.y,
                x1.z + y1.z + b1.z, x1.w + y1.w + b1.w};
  #pragma unroll
  for (int j = 0; j < 8; ++j) v[j] = (v[j] >= 0.f) ? v[j] : a * v[j];
  ((float4*)(Out + i))[0] = *(float4*)&v[0];
  ((float4*)(Out + i))[1] = *(float4*)&v[4];
}

// ---------------------------------------------------------------------------
// Fallback single-pass projection (R11-verified) if workspace is too small
// for split-K partials.
// ---------------------------------------------------------------------------
__global__ __launch_bounds__(256, 2)
void proj_prelu(const __hip_bfloat16* __restrict__ X,
                const __hip_bfloat16* __restrict__ Wb,
                const float* __restrict__ Bv,
                const float* __restrict__ Pa,
                float* __restrict__ Out)
{
  __shared__ __align__(16) __hip_bfloat16 xs[2][128 * 64];   // 32 KB
  __shared__ __align__(16) __hip_bfloat16 wsm[2][64 * 64];   // 16 KB

  const int m0   = blockIdx.x * 128;
  const int n0   = blockIdx.y * 64;
  const int tid  = threadIdx.x;
  const int wave = tid >> 6;
  const int wm   = wave >> 1;
  const int wn   = wave & 1;
  const int lane = tid & 63;
  const int ln   = lane & 15;
  const int qd   = lane >> 4;
  const int r0 = tid >> 3, cc = tid & 7;

  f32x4 acc[8] = {};

  uint4 xg0, xg1, xg2, xg3, wg0, wg1;
  #define LOADK(ko)                                                           \
    xg0 = *(const uint4*)(X  + (size_t)(m0 + r0     ) * EMB + (ko) + cc * 8); \
    xg1 = *(const uint4*)(X  + (size_t)(m0 + r0 + 32) * EMB + (ko) + cc * 8); \
    xg2 = *(const uint4*)(X  + (size_t)(m0 + r0 + 64) * EMB + (ko) + cc * 8); \
    xg3 = *(const uint4*)(X  + (size_t)(m0 + r0 + 96) * EMB + (ko) + cc * 8); \
    wg0 = *(const uint4*)(Wb + (size_t)(n0 + r0     ) * EMB + (ko) + cc * 8); \
    wg1 = *(const uint4*)(Wb + (size_t)(n0 + r0 + 32) * EMB + (ko) + cc * 8)
  #define STORELDS(buf)                                                       \
    *(uint4*)&xs [buf][swz(r0,      cc)] = xg0;                               \
    *(uint4*)&xs [buf][swz(r0 + 32, cc)] = xg1;                               \
    *(uint4*)&xs [buf][swz(r0 + 64, cc)] = xg2;                               \
    *(uint4*)&xs [buf][swz(r0 + 96, cc)] = xg3;                               \
    *(uint4*)&wsm[buf][swz(r0,      cc)] = wg0;                               \
    *(uint4*)&wsm[buf][swz(r0 + 32, cc)] = wg1

  LOADK(0);
  STORELDS(0);
  LOADK(64);
  __syncthreads();

  for (int kt = 0; kt < EMB / 64; ++kt) {
    const int cur = kt & 1;
    if (kt + 1 < EMB / 64) {
      STORELDS(1 - cur);
      if (kt + 2 < EMB / 64) {
        LOADK((kt + 2) * 64);
      }
    }
    #pragma unroll
    for (int ks2 = 0; ks2 < 2; ++ks2) {
      bf16x8 ax0 = *(const bf16x8*)&xs[cur][swz(wm * 64 +  0 + ln, ks2 * 4 + qd)];
      bf16x8 ax1 = *(const bf16x8*)&xs[cur][swz(wm * 64 + 16 + ln, ks2 * 4 + qd)];
      bf16x8 ax2 = *(const bf16x8*)&xs[cur][swz(wm * 64 + 32 + ln, ks2 * 4 + qd)];
      bf16x8 ax3 = *(const bf16x8*)&xs[cur][swz(wm * 64 + 48 + ln, ks2 * 4 + qd)];
      bf16x8 bw0 = *(const bf16x8*)&wsm[cur][swz(wn * 32 +  0 + ln, ks2 * 4 + qd)];
      bf16x8 bw1 = *(const bf16x8*)&wsm[cur][swz(wn * 32 + 16 + ln, ks2 * 4 + qd)];
      acc[0] = __builtin_amdgcn_mfma_f32_16x16x32_bf16(ax0, bw0, acc[0], 0, 0, 0);
      acc[1] = __builtin_amdgcn_mfma_f32_16x16x32_bf16(ax0, bw1, acc[1], 0, 0, 0);
      acc[2] = __builtin_amdgcn_mfma_f32_16x16x32_bf16(ax1, bw0, acc[2], 0, 0, 0);
      acc[3] = __builtin_amdgcn_mfma_f32_16x16x32_bf16(ax1, bw1, acc[3], 0, 0, 0);
      acc[4] = __builtin_amdgcn_mfma_f32_16x16x32_bf16(ax2, bw0, acc[4], 0, 0, 0);
      acc[5] = __builtin_amdgcn_mfma_f32_16x16x32_bf16(ax2, bw1, acc[5], 0, 0, 0);
      acc[6] = __builtin_amdgcn_mfma_f32_16x16x32_bf16(ax3, bw0, acc[6], 0, 0, 0);
      acc[7] = __builtin_amdgcn_mfma_f32_16x16x32_bf16(ax3, bw1, acc[7], 0, 0, 0);
    }
    __syncthreads();
  }

  const float a = Pa[0];
  #pragma unroll
  for (int mf = 0; mf < 4; ++mf) {
    #pragma unroll
    for (int nf = 0; nf < 2; ++nf) {
      const float bn = Bv[n0 + wn * 32 + nf * 16 + ln];
      #pragma unroll
      for (int r = 0; r < 4; ++r) {
        float y = acc[mf * 2 + nf][r] + bn;
        y = (y >= 0.f) ? y : a * y;
        Out[(size_t)(m0 + wm * 64 + mf * 16 + qd * 4 + r) * EMB +
            n0 + wn * 32 + nf * 16 + ln] = y;
      }
    }
  }
  #undef LOADK
  #undef STORELDS
}

extern "C" void kernel_launch(void* const* d_in, const int* in_sizes, int n_in,
                              void* d_out, int out_size, void* d_ws, size_t ws_size,
                              hipStream_t stream) {
  const float* Q  = (const float*)d_in[0];
  const float* K  = (const float*)d_in[1];
  const float* V  = (const float*)d_in[2];
  const float* W  = (const float*)d_in[3];
  const float* Bb = (const float*)d_in[4];
  const float* Pa = (const float*)d_in[5];
  float* Out = (float*)d_out;

  // workspace (bytes): X 0..8M, Kb 8..16M, Vt 16..24M, Wb 24..26M,
  //                    P0 28..44M, P1 46..62M (split-K partials, f32)
  char* ws = (char*)d_ws;
  __hip_bfloat16* Xws = (__hip_bfloat16*)(ws);
  __hip_bfloat16* Kb  = (__hip_bfloat16*)(ws + (8u  << 20));
  __hip_bfloat16* Vt  = (__hip_bfloat16*)(ws + (16u << 20));
  __hip_bfloat16* Wb  = (__hip_bfloat16*)(ws + (24u << 20));

  prep      <<<dim3(S_LEN / 64, NH, 3), 256, 0, stream>>>(K, V, W, Kb, Vt, Wb);
  attn_fwd  <<<dim3(S_LEN / 128, NH, 2), 512, 0, stream>>>(Q, Kb, Vt, Xws);

  if (ws_size >= (64ull << 20)) {
    float* P0 = (float*)(ws + (28ull << 20));
    float* P1 = (float*)(ws + (46ull << 20));
    proj_gemm  <<<dim3(2 * S_LEN / 128, EMB / 64, 2), 256, 0, stream>>>(Xws, Wb, P0, P1);
    proj_reduce<<<2 * S_LEN * EMB / (256 * 8), 256, 0, stream>>>(P0, P1, Bb, Pa, Out);
  } else {
    proj_prelu <<<dim3(2 * S_LEN / 128, EMB / 64), 256, 0, stream>>>(Xws, Wb, Bb, Pa, Out);
  }
}

// Round 6
// 156.222 us; speedup vs baseline: 1.0321x; 1.0321x over previous
//
#include <hip/hip_runtime.h>
#include <hip/hip_bf16.h>

typedef __attribute__((ext_vector_type(8))) short bf16x8;
typedef __attribute__((ext_vector_type(4))) float f32x4;

#define S_LEN 2048
#define EMB   1024
#define NH    16
#define HD    64

// XOR-swizzled LDS addressing: 64-col bf16 tiles, 8-elem (16 B) chunks.
// elem(row, chunk) = row*64 + ((chunk ^ (row&7))*8).
// Verified: SQ_LDS_BANK_CONFLICT == 0.
__device__ inline int swz(int row, int chunk) {
  return row * 64 + ((chunk ^ (row & 7)) << 3);
}

// 128-col variant (16 chunks/row) for the V tile [dim][key] at KVBLK=128.
__device__ inline int swz128(int row, int chunk) {
  return row * 128 + ((chunk ^ (row & 15)) << 3);
}

// K-row permutation: storing K row s at position [s5,s2,s4,s3,s1,s0] makes
// the exp(S^T) C-layout registers exactly the mfma_16x16x32 A-fragment for
// natural-order V; PV uses K=32 MFMA with b128 V reads, no fixup.
// At KVBLK=128 it applies within each 64-key half (bit 6 preserved).
__device__ inline int kperm(int s) {
  return (s & 0x23) | ((s & 0x04) << 2) | ((s & 0x18) >> 1);
}

// Convert 8 contiguous f32 -> 8 bf16 (RNE) packed in a uint4, optional scale.
__device__ inline uint4 cvt8(const float* __restrict__ src, float scale) {
  float4 f0 = ((const float4*)src)[0];
  float4 f1 = ((const float4*)src)[1];
  __hip_bfloat16 t[8];
  t[0] = __float2bfloat16(f0.x * scale);
  t[1] = __float2bfloat16(f0.y * scale);
  t[2] = __float2bfloat16(f0.z * scale);
  t[3] = __float2bfloat16(f0.w * scale);
  t[4] = __float2bfloat16(f1.x * scale);
  t[5] = __float2bfloat16(f1.y * scale);
  t[6] = __float2bfloat16(f1.z * scale);
  t[7] = __float2bfloat16(f1.w * scale);
  return *(uint4*)t;
}

// Register-resident variant: convert 8 f32 (already loaded) -> uint4 of bf16.
// Used so prefetch loads stay raw f32 in regs and the vmcnt wait lands at
// STORE time (one iteration later), preserving the prefetch distance.
__device__ inline uint4 cvt8r(float4 f0, float4 f1) {
  __hip_bfloat16 t[8];
  t[0] = __float2bfloat16(f0.x);
  t[1] = __float2bfloat16(f0.y);
  t[2] = __float2bfloat16(f0.z);
  t[3] = __float2bfloat16(f0.w);
  t[4] = __float2bfloat16(f1.x);
  t[5] = __float2bfloat16(f1.y);
  t[6] = __float2bfloat16(f1.z);
  t[7] = __float2bfloat16(f1.w);
  return *(uint4*)t;
}

__device__ inline void ld8f(const float* __restrict__ p, float4& a, float4& b) {
  a = ((const float4*)p)[0];
  b = ((const float4*)p)[1];
}

// ---------------------------------------------------------------------------
// prep (R15: V-transpose ONLY — K convert folded into attn staging, W convert
// folded into proj staging; deletes the Kb and Wb HBM round-trips).
//   Vt[((b*NH+h)*64 + d)*S + s]  (transposed, rows = dims)
// ---------------------------------------------------------------------------
__global__ __launch_bounds__(256)
void prep(const float* __restrict__ V, __hip_bfloat16* __restrict__ Vt) {
  __shared__ float vt[64 * 65];
  const int tid = threadIdx.x;
  const int st = blockIdx.x, h = blockIdx.y, b = blockIdx.z;
  const size_t srcbase = ((size_t)(b * S_LEN + st * 64)) * EMB + h * HD;
  const size_t vtb = ((size_t)(b * NH + h) * HD) * S_LEN + st * 64;

  for (int c = tid; c < 512; c += 256) {
    const int r = c >> 3, c8 = (c & 7) * 8;
    const float* vsrc = V + srcbase + (size_t)r * EMB + c8;
    float4 a = ((const float4*)vsrc)[0];
    float4 d4 = ((const float4*)vsrc)[1];
    float tv[8] = {a.x, a.y, a.z, a.w, d4.x, d4.y, d4.z, d4.w};
    #pragma unroll
    for (int j = 0; j < 8; ++j) vt[r * 65 + c8 + j] = tv[j];
  }
  __syncthreads();
  for (int c = tid; c < 512; c += 256) {
    const int d = c >> 3, s8 = (c & 7) * 8;
    __hip_bfloat16 t[8];
    #pragma unroll
    for (int j = 0; j < 8; ++j)
      t[j] = __float2bfloat16(vt[(s8 + j) * 65 + d]);
    *(uint4*)(Vt + vtb + (size_t)d * S_LEN + s8) = *(uint4*)t;
  }
}

// ---------------------------------------------------------------------------
// Flash attention, R15: R13 core verbatim (verified 46.5 us, absmax 4.88e-4)
// with ONE change: K is read directly from the f32 input (coalesced 32 B/lane
// row reads) and converted to bf16 at LDS-store time — kills the Kb HBM
// round-trip. f32 stays in regs across the prefetch window so the vmcnt wait
// still lands one iteration after issue. Core: 16 QK MFMAs back-to-back;
// exp/pack half-A; PV t=0,1 overlapping exp/pack half-B; PV t=2,3; setprio
// around MFMA clusters; raw v_exp_f32; lsum on the MFMA pipe; KVBLK=128,
// double-buffered, 1 barrier/iter, 80 KB LDS.
// ---------------------------------------------------------------------------
__global__ __launch_bounds__(512, 4)
void attn_fwd(const float* __restrict__ Q,
              const float* __restrict__ K,
              const __hip_bfloat16* __restrict__ Vt,
              __hip_bfloat16* __restrict__ O)
{
  __shared__ __align__(16) __hip_bfloat16 qs[128 * 64];      // 16 KB
  __shared__ __align__(16) __hip_bfloat16 ks[2][128 * 64];   // 32 KB [key][dim]
  __shared__ __align__(16) __hip_bfloat16 vs[2][64 * 128];   // 32 KB [dim][key]

  const int qt   = blockIdx.x;
  const int h    = blockIdx.y;
  const int b    = blockIdx.z;
  const int tid  = threadIdx.x;
  const int wave = tid >> 6;
  const int lane = tid & 63;
  const int ln   = lane & 15;
  const int qd   = lane >> 4;

  const size_t baseQ = ((size_t)(b * S_LEN + qt * 128)) * EMB + h * HD;
  const size_t baseK = ((size_t)(b * S_LEN)) * EMB + h * HD;   // f32 K rows
  const size_t vtb   = ((size_t)(b * NH + h) * HD) * S_LEN;

  // staging maps (loop-invariant write addrs)
  const int r0 = tid >> 3, cc = tid & 7;
  const int kpos0 = swz(kperm(r0), cc);
  const int kpos1 = kpos0 + 64 * 64;           // kperm within half, bit6 kept
  const int vr0 = tid >> 4, vch = tid & 15;
  const int vpos0 = swz128(vr0, vch);
  const int vpos1 = vpos0 + 32 * 128;          // (vr0+32)&15 == vr0&15

  // prefetch tile 0: K rows r0 and 64+r0 as raw f32 (8 floats each)
  float4 ka0, kb0, ka1, kb1;
  ld8f(K + baseK + (size_t)(r0)      * EMB + cc * 8, ka0, kb0);
  ld8f(K + baseK + (size_t)(64 + r0) * EMB + cc * 8, ka1, kb1);
  uint4 vreg0 = *(const uint4*)(Vt + vtb + (size_t)vr0        * S_LEN + vch * 8);
  uint4 vreg1 = *(const uint4*)(Vt + vtb + (size_t)(vr0 + 32) * S_LEN + vch * 8);

  // stage Q (f32 -> bf16, scale = 0.125*log2(e); P = exp2(S'))
  const float qscale = 0.125f * 1.44269504088896f;
  #pragma unroll
  for (int i = 0; i < 2; ++i) {
    const int c = tid + 512 * i, row = c >> 3, ch = c & 7;
    *(uint4*)&qs[swz(row, ch)] = cvt8(Q + baseQ + (size_t)row * EMB + ch * 8, qscale);
  }
  // write tile 0 (convert K at store time), prefetch tile 1
  *(uint4*)&ks[0][kpos0] = cvt8r(ka0, kb0);
  *(uint4*)&ks[0][kpos1] = cvt8r(ka1, kb1);
  *(uint4*)&vs[0][vpos0] = vreg0;
  *(uint4*)&vs[0][vpos1] = vreg1;
  ld8f(K + baseK + (size_t)(128 + r0) * EMB + cc * 8, ka0, kb0);
  ld8f(K + baseK + (size_t)(192 + r0) * EMB + cc * 8, ka1, kb1);
  vreg0 = *(const uint4*)(Vt + vtb + (size_t)vr0        * S_LEN + 128 + vch * 8);
  vreg1 = *(const uint4*)(Vt + vtb + (size_t)(vr0 + 32) * S_LEN + 128 + vch * 8);
  __syncthreads();   // qs + buf0 ready

  // Q B-fragments (n = query = ln, k = qd*8+j), loop-invariant
  bf16x8 aq[2];
  #pragma unroll
  for (int kh = 0; kh < 2; ++kh)
    aq[kh] = *(const bf16x8*)&qs[swz(wave * 16 + ln, kh * 4 + qd)];

  // ones B-fragment for lsum-on-MFMA: D[q][*] = sum_k P[q][k]
  bf16x8 ones;
  #pragma unroll
  for (int j = 0; j < 8; ++j) ones[j] = (short)0x3F80;   // bf16 1.0

  f32x4 oacc[4] = {};   // [dn]; C: col=dim=ln, row=query=qd*4+r
  f32x4 lacc = {};      // row sums; C: row=query=qd*4+r (col replicated)

  for (int kt = 0; kt < S_LEN / 128; ++kt) {
    const int cur = kt & 1;
    if (kt + 1 < S_LEN / 128) {     // regs loaded one full iter ago: no stall
      *(uint4*)&ks[1 - cur][kpos0] = cvt8r(ka0, kb0);
      *(uint4*)&ks[1 - cur][kpos1] = cvt8r(ka1, kb1);
      *(uint4*)&vs[1 - cur][vpos0] = vreg0;
      *(uint4*)&vs[1 - cur][vpos1] = vreg1;
      if (kt + 2 < S_LEN / 128) {
        const int kb2 = (kt + 2) * 128;
        ld8f(K + baseK + (size_t)(kb2 + r0)      * EMB + cc * 8, ka0, kb0);
        ld8f(K + baseK + (size_t)(kb2 + 64 + r0) * EMB + cc * 8, ka1, kb1);
        vreg0 = *(const uint4*)(Vt + vtb + (size_t)vr0        * S_LEN + kb2 + vch * 8);
        vreg1 = *(const uint4*)(Vt + vtb + (size_t)(vr0 + 32) * S_LEN + kb2 + vch * 8);
      }
    }

    // ---- S^T = K Q^T, both 64-key halves back-to-back: 16 independent
    // MFMAs fill the matrix pipe while the trans pipe is still free.
    f32x4 sfA[4], sfB[4];
    __builtin_amdgcn_s_setprio(1);
    #pragma unroll
    for (int k16 = 0; k16 < 4; ++k16) {
      const int krow = k16 * 16 + ln;
      bf16x8 ak0 = *(const bf16x8*)&ks[cur][swz(krow, qd)];
      bf16x8 ak1 = *(const bf16x8*)&ks[cur][swz(krow, 4 + qd)];
      f32x4 acc = {};
      acc = __builtin_amdgcn_mfma_f32_16x16x32_bf16(ak0, aq[0], acc, 0, 0, 0);
      sfA[k16] = __builtin_amdgcn_mfma_f32_16x16x32_bf16(ak1, aq[1], acc, 0, 0, 0);
    }
    #pragma unroll
    for (int k16 = 0; k16 < 4; ++k16) {
      const int krow = (4 + k16) * 16 + ln;
      bf16x8 ak0 = *(const bf16x8*)&ks[cur][swz(krow, qd)];
      bf16x8 ak1 = *(const bf16x8*)&ks[cur][swz(krow, 4 + qd)];
      f32x4 acc = {};
      acc = __builtin_amdgcn_mfma_f32_16x16x32_bf16(ak0, aq[0], acc, 0, 0, 0);
      sfB[k16] = __builtin_amdgcn_mfma_f32_16x16x32_bf16(ak1, aq[1], acc, 0, 0, 0);
    }
    __builtin_amdgcn_s_setprio(0);

    // ---- exp/pack half A -> apA[0..1] (trans pipe; overlaps QK-B tail) ----
    bf16x8 apA[2];
    #pragma unroll
    for (int t2 = 0; t2 < 2; ++t2)
      #pragma unroll
      for (int j = 0; j < 8; ++j) {
        const float p = __builtin_amdgcn_exp2f(sfA[t2 * 2 + (j >> 2)][j & 3]);
        __hip_bfloat16 hb = __float2bfloat16(p);
        apA[t2][j] = *(short*)&hb;
      }

    // ---- PV + lsum for t=0,1 (10 MFMA) — overlaps exp/pack of half B ----
    __builtin_amdgcn_s_setprio(1);
    #pragma unroll
    for (int t = 0; t < 2; ++t) {
      lacc = __builtin_amdgcn_mfma_f32_16x16x32_bf16(apA[t], ones, lacc, 0, 0, 0);
      #pragma unroll
      for (int dn = 0; dn < 4; ++dn) {
        bf16x8 bv = *(const bf16x8*)&vs[cur][swz128(dn * 16 + ln, t * 4 + qd)];
        oacc[dn] = __builtin_amdgcn_mfma_f32_16x16x32_bf16(apA[t], bv, oacc[dn], 0, 0, 0);
      }
    }
    __builtin_amdgcn_s_setprio(0);

    // ---- exp/pack half B -> apB[0..1] ----
    bf16x8 apB[2];
    #pragma unroll
    for (int t2 = 0; t2 < 2; ++t2)
      #pragma unroll
      for (int j = 0; j < 8; ++j) {
        const float p = __builtin_amdgcn_exp2f(sfB[t2 * 2 + (j >> 2)][j & 3]);
        __hip_bfloat16 hb = __float2bfloat16(p);
        apB[t2][j] = *(short*)&hb;
      }

    // ---- PV + lsum for t=2,3 ----
    __builtin_amdgcn_s_setprio(1);
    #pragma unroll
    for (int t = 0; t < 2; ++t) {
      lacc = __builtin_amdgcn_mfma_f32_16x16x32_bf16(apB[t], ones, lacc, 0, 0, 0);
      #pragma unroll
      for (int dn = 0; dn < 4; ++dn) {
        bf16x8 bv = *(const bf16x8*)&vs[cur][swz128(dn * 16 + ln, (2 + t) * 4 + qd)];
        oacc[dn] = __builtin_amdgcn_mfma_f32_16x16x32_bf16(apB[t], bv, oacc[dn], 0, 0, 0);
      }
    }
    __builtin_amdgcn_s_setprio(0);

    __syncthreads();   // single barrier per iteration
  }

  // ---- epilogue: lacc[r] is already this lane's row sums -> normalize ----
  #pragma unroll
  for (int r = 0; r < 4; ++r) {
    const float inv = 1.f / lacc[r];
    const int row = wave * 16 + qd * 4 + r;
    #pragma unroll
    for (int dn = 0; dn < 4; ++dn)
      O[baseQ + (size_t)row * EMB + dn * 16 + ln] =
          __float2bfloat16(oacc[dn][r] * inv);
  }
}

// ---------------------------------------------------------------------------
// Projection R15: single-pass (split-K reverted — R14 showed the K-loop is
// not the cost; split-K only added reduce traffic). W is read directly from
// the f32 input and converted at LDS-store time (kills the Wb round-trip);
// f32 stays in regs across the prefetch window. 128x64 tile, 512 blocks,
// 4 waves 2x2, 16 MFMA per 12 LDS reads per BK=64 iter, double-buffered,
// 1 barrier/iter, XOR swizzle, LDS 48 KB.
// ---------------------------------------------------------------------------
__global__ __launch_bounds__(256, 2)
void proj_prelu(const __hip_bfloat16* __restrict__ X,
                const float* __restrict__ W,
                const float* __restrict__ Bv,
                const float* __restrict__ Pa,
                float* __restrict__ Out)
{
  __shared__ __align__(16) __hip_bfloat16 xs[2][128 * 64];   // 32 KB
  __shared__ __align__(16) __hip_bfloat16 wsm[2][64 * 64];   // 16 KB

  const int m0   = blockIdx.x * 128;
  const int n0   = blockIdx.y * 64;
  const int tid  = threadIdx.x;
  const int wave = tid >> 6;
  const int wm   = wave >> 1;      // 0..1 : 64-row half
  const int wn   = wave & 1;       // 0..1 : 32-col half
  const int lane = tid & 63;
  const int ln   = lane & 15;
  const int qd   = lane >> 4;

  // staging: X 1024 chunks / 256 thr = 4 each; W 512 chunks = 2 each
  const int r0 = tid >> 3, cc = tid & 7;

  f32x4 acc[8] = {};   // [mf*2+nf]

  uint4 xg0, xg1, xg2, xg3;
  float4 wa0, wb0, wa1, wb1;
  #define LOADK(ko)                                                           \
    xg0 = *(const uint4*)(X  + (size_t)(m0 + r0     ) * EMB + (ko) + cc * 8); \
    xg1 = *(const uint4*)(X  + (size_t)(m0 + r0 + 32) * EMB + (ko) + cc * 8); \
    xg2 = *(const uint4*)(X  + (size_t)(m0 + r0 + 64) * EMB + (ko) + cc * 8); \
    xg3 = *(const uint4*)(X  + (size_t)(m0 + r0 + 96) * EMB + (ko) + cc * 8); \
    ld8f(W + (size_t)(n0 + r0     ) * EMB + (ko) + cc * 8, wa0, wb0);         \
    ld8f(W + (size_t)(n0 + r0 + 32) * EMB + (ko) + cc * 8, wa1, wb1)
  #define STORELDS(buf)                                                       \
    *(uint4*)&xs [buf][swz(r0,      cc)] = xg0;                               \
    *(uint4*)&xs [buf][swz(r0 + 32, cc)] = xg1;                               \
    *(uint4*)&xs [buf][swz(r0 + 64, cc)] = xg2;                               \
    *(uint4*)&xs [buf][swz(r0 + 96, cc)] = xg3;                               \
    *(uint4*)&wsm[buf][swz(r0,      cc)] = cvt8r(wa0, wb0);                   \
    *(uint4*)&wsm[buf][swz(r0 + 32, cc)] = cvt8r(wa1, wb1)

  LOADK(0);
  STORELDS(0);
  LOADK(64);
  __syncthreads();

  for (int kt = 0; kt < EMB / 64; ++kt) {
    const int cur = kt & 1;
    if (kt + 1 < EMB / 64) {
      STORELDS(1 - cur);
      if (kt + 2 < EMB / 64) {
        LOADK((kt + 2) * 64);
      }
    }

    #pragma unroll
    for (int ks2 = 0; ks2 < 2; ++ks2) {   // two K=32 steps
      bf16x8 ax0 = *(const bf16x8*)&xs[cur][swz(wm * 64 +  0 + ln, ks2 * 4 + qd)];
      bf16x8 ax1 = *(const bf16x8*)&xs[cur][swz(wm * 64 + 16 + ln, ks2 * 4 + qd)];
      bf16x8 ax2 = *(const bf16x8*)&xs[cur][swz(wm * 64 + 32 + ln, ks2 * 4 + qd)];
      bf16x8 ax3 = *(const bf16x8*)&xs[cur][swz(wm * 64 + 48 + ln, ks2 * 4 + qd)];
      bf16x8 bw0 = *(const bf16x8*)&wsm[cur][swz(wn * 32 +  0 + ln, ks2 * 4 + qd)];
      bf16x8 bw1 = *(const bf16x8*)&wsm[cur][swz(wn * 32 + 16 + ln, ks2 * 4 + qd)];
      acc[0] = __builtin_amdgcn_mfma_f32_16x16x32_bf16(ax0, bw0, acc[0], 0, 0, 0);
      acc[1] = __builtin_amdgcn_mfma_f32_16x16x32_bf16(ax0, bw1, acc[1], 0, 0, 0);
      acc[2] = __builtin_amdgcn_mfma_f32_16x16x32_bf16(ax1, bw0, acc[2], 0, 0, 0);
      acc[3] = __builtin_amdgcn_mfma_f32_16x16x32_bf16(ax1, bw1, acc[3], 0, 0, 0);
      acc[4] = __builtin_amdgcn_mfma_f32_16x16x32_bf16(ax2, bw0, acc[4], 0, 0, 0);
      acc[5] = __builtin_amdgcn_mfma_f32_16x16x32_bf16(ax2, bw1, acc[5], 0, 0, 0);
      acc[6] = __builtin_amdgcn_mfma_f32_16x16x32_bf16(ax3, bw0, acc[6], 0, 0, 0);
      acc[7] = __builtin_amdgcn_mfma_f32_16x16x32_bf16(ax3, bw1, acc[7], 0, 0, 0);
    }
    __syncthreads();
  }

  const float a = Pa[0];
  #pragma unroll
  for (int mf = 0; mf < 4; ++mf) {
    #pragma unroll
    for (int nf = 0; nf < 2; ++nf) {
      const float bn = Bv[n0 + wn * 32 + nf * 16 + ln];
      #pragma unroll
      for (int r = 0; r < 4; ++r) {
        float y = acc[mf * 2 + nf][r] + bn;
        y = (y >= 0.f) ? y : a * y;
        Out[(size_t)(m0 + wm * 64 + mf * 16 + qd * 4 + r) * EMB +
            n0 + wn * 32 + nf * 16 + ln] = y;
      }
    }
  }
  #undef LOADK
  #undef STORELDS
}

extern "C" void kernel_launch(void* const* d_in, const int* in_sizes, int n_in,
                              void* d_out, int out_size, void* d_ws, size_t ws_size,
                              hipStream_t stream) {
  const float* Q  = (const float*)d_in[0];
  const float* K  = (const float*)d_in[1];
  const float* V  = (const float*)d_in[2];
  const float* W  = (const float*)d_in[3];
  const float* Bb = (const float*)d_in[4];
  const float* Pa = (const float*)d_in[5];
  float* Out = (float*)d_out;

  // workspace (bytes): X 0..8M, Vt 16..24M (Kb/Wb slots retired in R15)
  char* ws = (char*)d_ws;
  __hip_bfloat16* Xws = (__hip_bfloat16*)(ws);
  __hip_bfloat16* Vt  = (__hip_bfloat16*)(ws + (16u << 20));

  prep      <<<dim3(S_LEN / 64, NH, 2), 256, 0, stream>>>(V, Vt);
  attn_fwd  <<<dim3(S_LEN / 128, NH, 2), 512, 0, stream>>>(Q, K, Vt, Xws);
  proj_prelu<<<dim3(2 * S_LEN / 128, EMB / 64), 256, 0, stream>>>(Xws, W, Bb, Pa, Out);
}

// Round 7
// 155.898 us; speedup vs baseline: 1.0342x; 1.0021x over previous
//
#include <hip/hip_runtime.h>
#include <hip/hip_bf16.h>

typedef __attribute__((ext_vector_type(8))) short bf16x8;
typedef __attribute__((ext_vector_type(4))) float f32x4;

#define S_LEN 2048
#define EMB   1024
#define NH    16
#define HD    64

// XOR-swizzled LDS addressing: 64-col bf16 tiles, 8-elem (16 B) chunks.
// elem(row, chunk) = row*64 + ((chunk ^ (row&7))*8). Verified: 0 conflicts.
__device__ inline int swz(int row, int chunk) {
  return row * 64 + ((chunk ^ (row & 7)) << 3);
}

// 128-col variant (16 chunks/row) for the V tile [dim][key] at KVBLK=128.
__device__ inline int swz128(int row, int chunk) {
  return row * 128 + ((chunk ^ (row & 15)) << 3);
}

// K-row permutation: storing K row s at position [s5,s2,s4,s3,s1,s0] makes
// the exp(S^T) C-layout registers exactly the mfma_16x16x32 A-fragment for
// natural-order V; PV uses K=32 MFMA with b128 V reads, no fixup.
// At KVBLK=128 it applies within each 64-key half (bit 6 preserved).
__device__ inline int kperm(int s) {
  return (s & 0x23) | ((s & 0x04) << 2) | ((s & 0x18) >> 1);
}

// Convert 8 contiguous f32 -> 8 bf16 (RNE) packed in a uint4, optional scale.
__device__ inline uint4 cvt8(const float* __restrict__ src, float scale) {
  float4 f0 = ((const float4*)src)[0];
  float4 f1 = ((const float4*)src)[1];
  __hip_bfloat16 t[8];
  t[0] = __float2bfloat16(f0.x * scale);
  t[1] = __float2bfloat16(f0.y * scale);
  t[2] = __float2bfloat16(f0.z * scale);
  t[3] = __float2bfloat16(f0.w * scale);
  t[4] = __float2bfloat16(f1.x * scale);
  t[5] = __float2bfloat16(f1.y * scale);
  t[6] = __float2bfloat16(f1.z * scale);
  t[7] = __float2bfloat16(f1.w * scale);
  return *(uint4*)t;
}

// Register-resident variant (for W-fold in proj staging).
__device__ inline uint4 cvt8r(float4 f0, float4 f1) {
  __hip_bfloat16 t[8];
  t[0] = __float2bfloat16(f0.x);
  t[1] = __float2bfloat16(f0.y);
  t[2] = __float2bfloat16(f0.z);
  t[3] = __float2bfloat16(f0.w);
  t[4] = __float2bfloat16(f1.x);
  t[5] = __float2bfloat16(f1.y);
  t[6] = __float2bfloat16(f1.z);
  t[7] = __float2bfloat16(f1.w);
  return *(uint4*)t;
}

__device__ inline void ld8f(const float* __restrict__ p, float4& a, float4& b) {
  a = ((const float4*)p)[0];
  b = ((const float4*)p)[1];
}

// ---------------------------------------------------------------------------
// prep (R16): K convert + V transpose (K-fold reverted — R15 measured +33 MB
// HBM and +5 us in attn from f32 strided K reads; bf16-packed Kb keeps the
// per-head working set L2/L3-resident). W stays folded into proj (that half
// of R15 was the winning half).
//   Kb[((b*NH+h)*S + s)*64 + d]  (head-major, rows = keys)
//   Vt[((b*NH+h)*64 + d)*S + s]  (transposed, rows = dims)
// ---------------------------------------------------------------------------
__global__ __launch_bounds__(256)
void prep(const float* __restrict__ K, const float* __restrict__ V,
          __hip_bfloat16* __restrict__ Kb, __hip_bfloat16* __restrict__ Vt) {
  __shared__ float vt[64 * 65];
  const int tid = threadIdx.x;
  const int st = blockIdx.x, h = blockIdx.y, b = blockIdx.z;
  const size_t srcbase = ((size_t)(b * S_LEN + st * 64)) * EMB + h * HD;
  const size_t kvb = ((size_t)(b * NH + h) * S_LEN + st * 64) * HD;
  const size_t vtb = ((size_t)(b * NH + h) * HD) * S_LEN + st * 64;

  for (int c = tid; c < 512; c += 256) {
    const int r = c >> 3, c8 = (c & 7) * 8;
    *(uint4*)(Kb + kvb + r * HD + c8) = cvt8(K + srcbase + (size_t)r * EMB + c8, 1.0f);
    const float* vsrc = V + srcbase + (size_t)r * EMB + c8;
    float4 a = ((const float4*)vsrc)[0];
    float4 d4 = ((const float4*)vsrc)[1];
    float tv[8] = {a.x, a.y, a.z, a.w, d4.x, d4.y, d4.z, d4.w};
    #pragma unroll
    for (int j = 0; j < 8; ++j) vt[r * 65 + c8 + j] = tv[j];
  }
  __syncthreads();
  for (int c = tid; c < 512; c += 256) {
    const int d = c >> 3, s8 = (c & 7) * 8;
    __hip_bfloat16 t[8];
    #pragma unroll
    for (int j = 0; j < 8; ++j)
      t[j] = __float2bfloat16(vt[(s8 + j) * 65 + d]);
    *(uint4*)(Vt + vtb + (size_t)d * S_LEN + s8) = *(uint4*)t;
  }
}

// ---------------------------------------------------------------------------
// Flash attention, R16: cross-iteration pipeline (T15 form). PV of each
// tile's SECOND half (t=2,3) is deferred one iteration: its V-fragments are
// saved to registers (bvD, 32 VGPR) before the LDS buffer is overwritten and
// its P-fragments carried (apD). Every exp phase now has an MFMA partner:
//   expA(kt) ∥ {deferred PV-B(kt-1) + QK-B(kt)},  expB(kt) ∥ PV-A(kt).
// Accumulation order (0A,0B,1A,1B,...) is IDENTICAL to R13 -> bit-identical
// output. apD/bvD zero-init makes iter-0's deferred pass a no-op (0x0).
// QK split into two 8-MFMA clusters to shorten sf live ranges (VGPR < 128).
// Staging = R13 verbatim (Kb bf16 reads). KVBLK=128, double-buffered,
// 1 barrier/iter, 80 KB LDS, lsum on the MFMA pipe, raw v_exp_f32.
// ---------------------------------------------------------------------------
__global__ __launch_bounds__(512, 4)
void attn_fwd(const float* __restrict__ Q,
              const __hip_bfloat16* __restrict__ Kb,
              const __hip_bfloat16* __restrict__ Vt,
              __hip_bfloat16* __restrict__ O)
{
  __shared__ __align__(16) __hip_bfloat16 qs[128 * 64];      // 16 KB
  __shared__ __align__(16) __hip_bfloat16 ks[2][128 * 64];   // 32 KB [key][dim]
  __shared__ __align__(16) __hip_bfloat16 vs[2][64 * 128];   // 32 KB [dim][key]

  const int qt   = blockIdx.x;
  const int h    = blockIdx.y;
  const int b    = blockIdx.z;
  const int tid  = threadIdx.x;
  const int wave = tid >> 6;
  const int lane = tid & 63;
  const int ln   = lane & 15;
  const int qd   = lane >> 4;

  const size_t baseQ = ((size_t)(b * S_LEN + qt * 128)) * EMB + h * HD;
  const size_t kvb   = ((size_t)(b * NH + h) * S_LEN) * HD;
  const size_t vtb   = ((size_t)(b * NH + h) * HD) * S_LEN;

  // staging maps (loop-invariant write addrs)
  const int r0 = tid >> 3, cc = tid & 7;
  const int kpos0 = swz(kperm(r0), cc);
  const int kpos1 = kpos0 + 64 * 64;           // kperm within half, bit6 kept
  const int vr0 = tid >> 4, vch = tid & 15;
  const int vpos0 = swz128(vr0, vch);
  const int vpos1 = vpos0 + 32 * 128;          // (vr0+32)&15 == vr0&15

  // prefetch tile 0
  uint4 kreg0 = *(const uint4*)(Kb + kvb + (size_t)(r0)       * HD + cc * 8);
  uint4 kreg1 = *(const uint4*)(Kb + kvb + (size_t)(64 + r0)  * HD + cc * 8);
  uint4 vreg0 = *(const uint4*)(Vt + vtb + (size_t)vr0        * S_LEN + vch * 8);
  uint4 vreg1 = *(const uint4*)(Vt + vtb + (size_t)(vr0 + 32) * S_LEN + vch * 8);

  // stage Q (f32 -> bf16, scale = 0.125*log2(e); P = exp2(S'))
  const float qscale = 0.125f * 1.44269504088896f;
  #pragma unroll
  for (int i = 0; i < 2; ++i) {
    const int c = tid + 512 * i, row = c >> 3, ch = c & 7;
    *(uint4*)&qs[swz(row, ch)] = cvt8(Q + baseQ + (size_t)row * EMB + ch * 8, qscale);
  }
  // write tile 0, prefetch tile 1
  *(uint4*)&ks[0][kpos0] = kreg0;
  *(uint4*)&ks[0][kpos1] = kreg1;
  *(uint4*)&vs[0][vpos0] = vreg0;
  *(uint4*)&vs[0][vpos1] = vreg1;
  kreg0 = *(const uint4*)(Kb + kvb + (size_t)(128 + r0)      * HD + cc * 8);
  kreg1 = *(const uint4*)(Kb + kvb + (size_t)(192 + r0)      * HD + cc * 8);
  vreg0 = *(const uint4*)(Vt + vtb + (size_t)vr0        * S_LEN + 128 + vch * 8);
  vreg1 = *(const uint4*)(Vt + vtb + (size_t)(vr0 + 32) * S_LEN + 128 + vch * 8);
  __syncthreads();   // qs + buf0 ready

  // Q B-fragments (n = query = ln, k = qd*8+j), loop-invariant
  bf16x8 aq[2];
  #pragma unroll
  for (int kh = 0; kh < 2; ++kh)
    aq[kh] = *(const bf16x8*)&qs[swz(wave * 16 + ln, kh * 4 + qd)];

  // ones B-fragment for lsum-on-MFMA: D[q][*] = sum_k P[q][k]
  bf16x8 ones;
  #pragma unroll
  for (int j = 0; j < 8; ++j) ones[j] = (short)0x3F80;   // bf16 1.0

  f32x4 oacc[4] = {};   // [dn]; C: col=dim=ln, row=query=qd*4+r
  f32x4 lacc = {};      // row sums; C: row=query=qd*4+r (col replicated)
  bf16x8 apD[2] = {};   // deferred P fragments (t=2,3 of prev tile); 0 = no-op
  bf16x8 bvD[8] = {};   // deferred V fragments [t*4+dn]; 0 so 0x0=0 (no NaN)

  for (int kt = 0; kt < S_LEN / 128; ++kt) {
    const int cur = kt & 1;
    if (kt + 1 < S_LEN / 128) {     // regs loaded one full iter ago: no stall
      *(uint4*)&ks[1 - cur][kpos0] = kreg0;
      *(uint4*)&ks[1 - cur][kpos1] = kreg1;
      *(uint4*)&vs[1 - cur][vpos0] = vreg0;
      *(uint4*)&vs[1 - cur][vpos1] = vreg1;
      if (kt + 2 < S_LEN / 128) {
        const int kb2 = (kt + 2) * 128;
        kreg0 = *(const uint4*)(Kb + kvb + (size_t)(kb2 + r0)       * HD + cc * 8);
        kreg1 = *(const uint4*)(Kb + kvb + (size_t)(kb2 + 64 + r0)  * HD + cc * 8);
        vreg0 = *(const uint4*)(Vt + vtb + (size_t)vr0        * S_LEN + kb2 + vch * 8);
        vreg1 = *(const uint4*)(Vt + vtb + (size_t)(vr0 + 32) * S_LEN + kb2 + vch * 8);
      }
    }

    // ---- QK half A: S^T rows 0..63 (8 MFMA) ----
    f32x4 sfA[4];
    __builtin_amdgcn_s_setprio(1);
    #pragma unroll
    for (int k16 = 0; k16 < 4; ++k16) {
      const int krow = k16 * 16 + ln;
      bf16x8 ak0 = *(const bf16x8*)&ks[cur][swz(krow, qd)];
      bf16x8 ak1 = *(const bf16x8*)&ks[cur][swz(krow, 4 + qd)];
      f32x4 acc = {};
      acc = __builtin_amdgcn_mfma_f32_16x16x32_bf16(ak0, aq[0], acc, 0, 0, 0);
      sfA[k16] = __builtin_amdgcn_mfma_f32_16x16x32_bf16(ak1, aq[1], acc, 0, 0, 0);
    }
    __builtin_amdgcn_s_setprio(0);

    // ---- expA -> apA (trans; overlaps QK-A tail + next MFMA cluster) ----
    bf16x8 apA[2];
    #pragma unroll
    for (int t2 = 0; t2 < 2; ++t2)
      #pragma unroll
      for (int j = 0; j < 8; ++j) {
        const float p = __builtin_amdgcn_exp2f(sfA[t2 * 2 + (j >> 2)][j & 3]);
        __hip_bfloat16 hb = __float2bfloat16(p);
        apA[t2][j] = *(short*)&hb;
      }

    // ---- deferred PV-B(kt-1) from regs + QK half B: one 18-MFMA cluster,
    //      independent of expA -> scheduler interleaves with it ----
    f32x4 sfB[4];
    __builtin_amdgcn_s_setprio(1);
    #pragma unroll
    for (int t = 0; t < 2; ++t) {
      lacc = __builtin_amdgcn_mfma_f32_16x16x32_bf16(apD[t], ones, lacc, 0, 0, 0);
      #pragma unroll
      for (int dn = 0; dn < 4; ++dn)
        oacc[dn] = __builtin_amdgcn_mfma_f32_16x16x32_bf16(apD[t], bvD[t * 4 + dn], oacc[dn], 0, 0, 0);
    }
    #pragma unroll
    for (int k16 = 0; k16 < 4; ++k16) {
      const int krow = (4 + k16) * 16 + ln;
      bf16x8 ak0 = *(const bf16x8*)&ks[cur][swz(krow, qd)];
      bf16x8 ak1 = *(const bf16x8*)&ks[cur][swz(krow, 4 + qd)];
      f32x4 acc = {};
      acc = __builtin_amdgcn_mfma_f32_16x16x32_bf16(ak0, aq[0], acc, 0, 0, 0);
      sfB[k16] = __builtin_amdgcn_mfma_f32_16x16x32_bf16(ak1, aq[1], acc, 0, 0, 0);
    }
    __builtin_amdgcn_s_setprio(0);

    // ---- expB -> apB (overlaps PV-A cluster below) ----
    bf16x8 apB[2];
    #pragma unroll
    for (int t2 = 0; t2 < 2; ++t2)
      #pragma unroll
      for (int j = 0; j < 8; ++j) {
        const float p = __builtin_amdgcn_exp2f(sfB[t2 * 2 + (j >> 2)][j & 3]);
        __hip_bfloat16 hb = __float2bfloat16(p);
        apB[t2][j] = *(short*)&hb;
      }

    // ---- PV-A(kt): t=0,1 via LDS reads (10 MFMA) ----
    __builtin_amdgcn_s_setprio(1);
    #pragma unroll
    for (int t = 0; t < 2; ++t) {
      lacc = __builtin_amdgcn_mfma_f32_16x16x32_bf16(apA[t], ones, lacc, 0, 0, 0);
      #pragma unroll
      for (int dn = 0; dn < 4; ++dn) {
        bf16x8 bv = *(const bf16x8*)&vs[cur][swz128(dn * 16 + ln, t * 4 + qd)];
        oacc[dn] = __builtin_amdgcn_mfma_f32_16x16x32_bf16(apA[t], bv, oacc[dn], 0, 0, 0);
      }
    }
    __builtin_amdgcn_s_setprio(0);

    // ---- save deferred state: V frags t=2,3 -> regs (before buffer reuse);
    //      ds latency hidden across the barrier + next QK/exp phases ----
    #pragma unroll
    for (int t = 0; t < 2; ++t)
      #pragma unroll
      for (int dn = 0; dn < 4; ++dn)
        bvD[t * 4 + dn] = *(const bf16x8*)&vs[cur][swz128(dn * 16 + ln, (2 + t) * 4 + qd)];
    apD[0] = apB[0];
    apD[1] = apB[1];

    __syncthreads();   // single barrier per iteration
  }

  // ---- epilogue: final deferred PV-B, then normalize ----
  #pragma unroll
  for (int t = 0; t < 2; ++t) {
    lacc = __builtin_amdgcn_mfma_f32_16x16x32_bf16(apD[t], ones, lacc, 0, 0, 0);
    #pragma unroll
    for (int dn = 0; dn < 4; ++dn)
      oacc[dn] = __builtin_amdgcn_mfma_f32_16x16x32_bf16(apD[t], bvD[t * 4 + dn], oacc[dn], 0, 0, 0);
  }
  #pragma unroll
  for (int r = 0; r < 4; ++r) {
    const float inv = 1.f / lacc[r];
    const int row = wave * 16 + qd * 4 + r;
    #pragma unroll
    for (int dn = 0; dn < 4; ++dn)
      O[baseQ + (size_t)row * EMB + dn * 16 + ln] =
          __float2bfloat16(oacc[dn][r] * inv);
  }
}

// ---------------------------------------------------------------------------
// Projection R16 (= R15, kept): W read directly from f32 input, converted at
// LDS-store time (no Wb round-trip). 128x64 tile, 512 blocks, 4 waves 2x2,
// 16 MFMA per 12 LDS reads per BK=64 iter, double-buffered, 1 barrier/iter,
// XOR swizzle, LDS 48 KB.
// ---------------------------------------------------------------------------
__global__ __launch_bounds__(256, 2)
void proj_prelu(const __hip_bfloat16* __restrict__ X,
                const float* __restrict__ W,
                const float* __restrict__ Bv,
                const float* __restrict__ Pa,
                float* __restrict__ Out)
{
  __shared__ __align__(16) __hip_bfloat16 xs[2][128 * 64];   // 32 KB
  __shared__ __align__(16) __hip_bfloat16 wsm[2][64 * 64];   // 16 KB

  const int m0   = blockIdx.x * 128;
  const int n0   = blockIdx.y * 64;
  const int tid  = threadIdx.x;
  const int wave = tid >> 6;
  const int wm   = wave >> 1;      // 0..1 : 64-row half
  const int wn   = wave & 1;       // 0..1 : 32-col half
  const int lane = tid & 63;
  const int ln   = lane & 15;
  const int qd   = lane >> 4;

  // staging: X 1024 chunks / 256 thr = 4 each; W 512 chunks = 2 each
  const int r0 = tid >> 3, cc = tid & 7;

  f32x4 acc[8] = {};   // [mf*2+nf]

  uint4 xg0, xg1, xg2, xg3;
  float4 wa0, wb0, wa1, wb1;
  #define LOADK(ko)                                                           \
    xg0 = *(const uint4*)(X  + (size_t)(m0 + r0     ) * EMB + (ko) + cc * 8); \
    xg1 = *(const uint4*)(X  + (size_t)(m0 + r0 + 32) * EMB + (ko) + cc * 8); \
    xg2 = *(const uint4*)(X  + (size_t)(m0 + r0 + 64) * EMB + (ko) + cc * 8); \
    xg3 = *(const uint4*)(X  + (size_t)(m0 + r0 + 96) * EMB + (ko) + cc * 8); \
    ld8f(W + (size_t)(n0 + r0     ) * EMB + (ko) + cc * 8, wa0, wb0);         \
    ld8f(W + (size_t)(n0 + r0 + 32) * EMB + (ko) + cc * 8, wa1, wb1)
  #define STORELDS(buf)                                                       \
    *(uint4*)&xs [buf][swz(r0,      cc)] = xg0;                               \
    *(uint4*)&xs [buf][swz(r0 + 32, cc)] = xg1;                               \
    *(uint4*)&xs [buf][swz(r0 + 64, cc)] = xg2;                               \
    *(uint4*)&xs [buf][swz(r0 + 96, cc)] = xg3;                               \
    *(uint4*)&wsm[buf][swz(r0,      cc)] = cvt8r(wa0, wb0);                   \
    *(uint4*)&wsm[buf][swz(r0 + 32, cc)] = cvt8r(wa1, wb1)

  LOADK(0);
  STORELDS(0);
  LOADK(64);
  __syncthreads();

  for (int kt = 0; kt < EMB / 64; ++kt) {
    const int cur = kt & 1;
    if (kt + 1 < EMB / 64) {
      STORELDS(1 - cur);
      if (kt + 2 < EMB / 64) {
        LOADK((kt + 2) * 64);
      }
    }

    #pragma unroll
    for (int ks2 = 0; ks2 < 2; ++ks2) {   // two K=32 steps
      bf16x8 ax0 = *(const bf16x8*)&xs[cur][swz(wm * 64 +  0 + ln, ks2 * 4 + qd)];
      bf16x8 ax1 = *(const bf16x8*)&xs[cur][swz(wm * 64 + 16 + ln, ks2 * 4 + qd)];
      bf16x8 ax2 = *(const bf16x8*)&xs[cur][swz(wm * 64 + 32 + ln, ks2 * 4 + qd)];
      bf16x8 ax3 = *(const bf16x8*)&xs[cur][swz(wm * 64 + 48 + ln, ks2 * 4 + qd)];
      bf16x8 bw0 = *(const bf16x8*)&wsm[cur][swz(wn * 32 +  0 + ln, ks2 * 4 + qd)];
      bf16x8 bw1 = *(const bf16x8*)&wsm[cur][swz(wn * 32 + 16 + ln, ks2 * 4 + qd)];
      acc[0] = __builtin_amdgcn_mfma_f32_16x16x32_bf16(ax0, bw0, acc[0], 0, 0, 0);
      acc[1] = __builtin_amdgcn_mfma_f32_16x16x32_bf16(ax0, bw1, acc[1], 0, 0, 0);
      acc[2] = __builtin_amdgcn_mfma_f32_16x16x32_bf16(ax1, bw0, acc[2], 0, 0, 0);
      acc[3] = __builtin_amdgcn_mfma_f32_16x16x32_bf16(ax1, bw1, acc[3], 0, 0, 0);
      acc[4] = __builtin_amdgcn_mfma_f32_16x16x32_bf16(ax2, bw0, acc[4], 0, 0, 0);
      acc[5] = __builtin_amdgcn_mfma_f32_16x16x32_bf16(ax2, bw1, acc[5], 0, 0, 0);
      acc[6] = __builtin_amdgcn_mfma_f32_16x16x32_bf16(ax3, bw0, acc[6], 0, 0, 0);
      acc[7] = __builtin_amdgcn_mfma_f32_16x16x32_bf16(ax3, bw1, acc[7], 0, 0, 0);
    }
    __syncthreads();
  }

  const float a = Pa[0];
  #pragma unroll
  for (int mf = 0; mf < 4; ++mf) {
    #pragma unroll
    for (int nf = 0; nf < 2; ++nf) {
      const float bn = Bv[n0 + wn * 32 + nf * 16 + ln];
      #pragma unroll
      for (int r = 0; r < 4; ++r) {
        float y = acc[mf * 2 + nf][r] + bn;
        y = (y >= 0.f) ? y : a * y;
        Out[(size_t)(m0 + wm * 64 + mf * 16 + qd * 4 + r) * EMB +
            n0 + wn * 32 + nf * 16 + ln] = y;
      }
    }
  }
  #undef LOADK
  #undef STORELDS
}

extern "C" void kernel_launch(void* const* d_in, const int* in_sizes, int n_in,
                              void* d_out, int out_size, void* d_ws, size_t ws_size,
                              hipStream_t stream) {
  const float* Q  = (const float*)d_in[0];
  const float* K  = (const float*)d_in[1];
  const float* V  = (const float*)d_in[2];
  const float* W  = (const float*)d_in[3];
  const float* Bb = (const float*)d_in[4];
  const float* Pa = (const float*)d_in[5];
  float* Out = (float*)d_out;

  // workspace (bytes): X 0..8M, Kb 8..16M, Vt 16..24M
  char* ws = (char*)d_ws;
  __hip_bfloat16* Xws = (__hip_bfloat16*)(ws);
  __hip_bfloat16* Kb  = (__hip_bfloat16*)(ws + (8u  << 20));
  __hip_bfloat16* Vt  = (__hip_bfloat16*)(ws + (16u << 20));

  prep      <<<dim3(S_LEN / 64, NH, 2), 256, 0, stream>>>(K, V, Kb, Vt);
  attn_fwd  <<<dim3(S_LEN / 128, NH, 2), 512, 0, stream>>>(Q, Kb, Vt, Xws);
  proj_prelu<<<dim3(2 * S_LEN / 128, EMB / 64), 256, 0, stream>>>(Xws, W, Bb, Pa, Out);
}